// Round 2
// baseline (536.682 us; speedup 1.0000x reference)
//
#include <hip/hip_runtime.h>
#include <math.h>

#define NB 8
#define NC 512
#define NN 2048

static constexpr int TM = 128, TN = 128, KB = 16;

__device__ __forceinline__ unsigned f2mono(float v) {
    unsigned b = __float_as_uint(v);
    return (b & 0x80000000u) ? ~b : (b | 0x80000000u);
}

// ---------------- Kernel 1: scores GEMM + fused gumbel argmax ----------------
// 128x128 tile, 8x8 per thread, single LDS buffer + register double-buffer.
extern "C" __global__ __launch_bounds__(256, 4)
void scores_argmax(const float* __restrict__ srcE,
                   const float* __restrict__ tgtE,
                   const float* __restrict__ gum,
                   const float* __restrict__ temp,
                   unsigned long long* __restrict__ best)
{
    __shared__ __align__(16) float As[KB][TM];
    __shared__ __align__(16) float Bs[KB][TN];
    const int b  = blockIdx.z;
    const int n0 = blockIdx.x * TM;
    const int m0 = blockIdx.y * TN;
    const int tid = threadIdx.x;
    const int tx = tid & 15, ty = tid >> 4;   // 16x16 threads, 8x8 each

    // staging: 2048 floats per tile per k-step = 512 float4; 256 threads x2
    const int lc  = (tid & 31) * 4;   // col (contig float4 across 32 lanes)
    const int lk0 = tid >> 5;         // rows lk0 and lk0+8

    const float* Ag = srcE + (size_t)b * NC * NN + n0 + lc;
    const float* Bg = tgtE + (size_t)b * NC * NN + m0 + lc;

    float4 pa0, pa1, pb0, pb1;
    pa0 = *(const float4*)(Ag + (size_t)lk0 * NN);
    pa1 = *(const float4*)(Ag + (size_t)(lk0 + 8) * NN);
    pb0 = *(const float4*)(Bg + (size_t)lk0 * NN);
    pb1 = *(const float4*)(Bg + (size_t)(lk0 + 8) * NN);

    float acc[8][8] = {};
    for (int k0 = 0; k0 < NC; k0 += KB) {
        __syncthreads();   // readers of previous tile done
        *(float4*)&As[lk0][lc]     = pa0;
        *(float4*)&As[lk0 + 8][lc] = pa1;
        *(float4*)&Bs[lk0][lc]     = pb0;
        *(float4*)&Bs[lk0 + 8][lc] = pb1;
        if (k0 + KB < NC) {   // prefetch next tile; latency hides under compute
            pa0 = *(const float4*)(Ag + (size_t)(k0 + KB + lk0) * NN);
            pa1 = *(const float4*)(Ag + (size_t)(k0 + KB + lk0 + 8) * NN);
            pb0 = *(const float4*)(Bg + (size_t)(k0 + KB + lk0) * NN);
            pb1 = *(const float4*)(Bg + (size_t)(k0 + KB + lk0 + 8) * NN);
        }
        __syncthreads();   // tile ready
#pragma unroll
        for (int k = 0; k < KB; ++k) {
            const float4 a0 = *(const float4*)&As[k][ty * 8];
            const float4 a1 = *(const float4*)&As[k][ty * 8 + 4];
            const float4 b0 = *(const float4*)&Bs[k][tx * 8];
            const float4 b1 = *(const float4*)&Bs[k][tx * 8 + 4];
            const float av[8] = {a0.x, a0.y, a0.z, a0.w, a1.x, a1.y, a1.z, a1.w};
            const float bv[8] = {b0.x, b0.y, b0.z, b0.w, b1.x, b1.y, b1.z, b1.w};
#pragma unroll
            for (int i = 0; i < 8; ++i)
#pragma unroll
                for (int j = 0; j < 8; ++j)
                    acc[i][j] = fmaf(av[i], bv[j], acc[i][j]);
        }
    }

    // ---- fused gumbel + per-row argmax ----
    const float SCL = 0.044194173824159216f;  // 1/sqrt(512)
    const float tau = temp[b];
#pragma unroll
    for (int i = 0; i < 8; ++i) {
        const int n = n0 + ty * 8 + i;
        const float* gr = gum + ((size_t)(b * NN + n)) * NN + m0 + tx * 8;
        const float4 u0 = *(const float4*)gr;
        const float4 u1 = *(const float4*)(gr + 4);
        const float uu[8] = {u0.x, u0.y, u0.z, u0.w, u1.x, u1.y, u1.z, u1.w};
        unsigned long long bp = 0ULL;
#pragma unroll
        for (int j = 0; j < 8; ++j) {
            float u = fminf(fmaxf(uu[j], 1e-6f), 1.0f - 1e-6f);
            float g = -logf(-logf(u));
            float val = (acc[i][j] * SCL + g) / tau;
            const int m = m0 + tx * 8 + j;
            unsigned long long p =
                ((unsigned long long)f2mono(val) << 32) | (unsigned)(NN - 1 - m);
            bp = (p > bp) ? p : bp;
        }
#pragma unroll
        for (int off = 8; off > 0; off >>= 1) {
            unsigned long long o = __shfl_xor(bp, off, 16);
            bp = (o > bp) ? o : bp;
        }
        if (tx == 0) atomicMax(&best[(size_t)b * NN + n], bp);
    }
}

// ---------------- Kernel 2: gather + covariance + 3x3 SVD + R,t ----------------
__device__ __forceinline__ double det3(const double M[3][3]) {
    return M[0][0] * (M[1][1] * M[2][2] - M[1][2] * M[2][1])
         - M[0][1] * (M[1][0] * M[2][2] - M[1][2] * M[2][0])
         + M[0][2] * (M[1][0] * M[2][1] - M[1][1] * M[2][0]);
}

extern "C" __global__ __launch_bounds__(256)
void assemble(const float* __restrict__ src, const float* __restrict__ tgt,
              const unsigned long long* __restrict__ best, float* __restrict__ out)
{
    const int b = blockIdx.x;
    const int tid = threadIdx.x;
    float P[9] = {}, Ss[3] = {}, Sc[3] = {};
    for (int n = tid; n < NN; n += 256) {
        const int m = (NN - 1) - (int)(unsigned)(best[(size_t)b * NN + n] & 0xffffffffu);
        float sv[3], cv[3];
#pragma unroll
        for (int c = 0; c < 3; ++c) {
            sv[c] = src[((size_t)b * 3 + c) * NN + n];
            cv[c] = tgt[((size_t)b * 3 + c) * NN + m];
            Ss[c] += sv[c];
            Sc[c] += cv[c];
        }
#pragma unroll
        for (int c = 0; c < 3; ++c)
#pragma unroll
            for (int d = 0; d < 3; ++d)
                P[c * 3 + d] = fmaf(sv[c], cv[d], P[c * 3 + d]);
    }

    float vals[15];
#pragma unroll
    for (int i = 0; i < 9; ++i) vals[i] = P[i];
#pragma unroll
    for (int i = 0; i < 3; ++i) { vals[9 + i] = Ss[i]; vals[12 + i] = Sc[i]; }

    __shared__ float red[4][15];
    const int lane = tid & 63, wv = tid >> 6;
#pragma unroll
    for (int i = 0; i < 15; ++i) {
        float v = vals[i];
        for (int off = 32; off > 0; off >>= 1) v += __shfl_down(v, off, 64);
        if (lane == 0) red[wv][i] = v;
    }
    __syncthreads();

    if (tid == 0) {
        double tot[15];
        for (int i = 0; i < 15; ++i)
            tot[i] = (double)red[0][i] + red[1][i] + red[2][i] + red[3][i];
        double smean[3], cmean[3], H[3][3];
        for (int c = 0; c < 3; ++c) { smean[c] = tot[9 + c] / NN; cmean[c] = tot[12 + c] / NN; }
        for (int c = 0; c < 3; ++c)
            for (int d = 0; d < 3; ++d)
                H[c][d] = tot[c * 3 + d] - tot[9 + c] * tot[12 + d] / NN;

        // one-sided Jacobi SVD on columns of W: H = U S V^T
        double W[3][3], V[3][3];
        for (int i = 0; i < 3; ++i)
            for (int j = 0; j < 3; ++j) { W[i][j] = H[i][j]; V[i][j] = (i == j) ? 1.0 : 0.0; }
        for (int sweep = 0; sweep < 60; ++sweep) {
            double offsum = 0.0;
            for (int p = 0; p < 2; ++p)
                for (int q = p + 1; q < 3; ++q) {
                    double al = 0, be = 0, ga = 0;
                    for (int r = 0; r < 3; ++r) {
                        al += W[r][p] * W[r][p];
                        be += W[r][q] * W[r][q];
                        ga += W[r][p] * W[r][q];
                    }
                    offsum += fabs(ga);
                    if (fabs(ga) <= 1e-15 * sqrt(al * be)) continue;
                    double zeta = (be - al) / (2.0 * ga);
                    double t = copysign(1.0, zeta) / (fabs(zeta) + sqrt(1.0 + zeta * zeta));
                    double c = 1.0 / sqrt(1.0 + t * t), s = c * t;
                    for (int r = 0; r < 3; ++r) {
                        double wp = W[r][p], wq = W[r][q];
                        W[r][p] = c * wp - s * wq;
                        W[r][q] = s * wp + c * wq;
                        double vp = V[r][p], vq = V[r][q];
                        V[r][p] = c * vp - s * vq;
                        V[r][q] = s * vp + c * vq;
                    }
                }
            if (offsum < 1e-13) break;
        }
        double S[3];
        for (int i = 0; i < 3; ++i)
            S[i] = sqrt(W[0][i] * W[0][i] + W[1][i] * W[1][i] + W[2][i] * W[2][i]);
        for (int i = 0; i < 2; ++i) {
            int mx = i;
            for (int j = i + 1; j < 3; ++j) if (S[j] > S[mx]) mx = j;
            if (mx != i) {
                double tS = S[i]; S[i] = S[mx]; S[mx] = tS;
                for (int r = 0; r < 3; ++r) {
                    double tw = W[r][i]; W[r][i] = W[r][mx]; W[r][mx] = tw;
                    double tv = V[r][i]; V[r][i] = V[r][mx]; V[r][mx] = tv;
                }
            }
        }
        double U[3][3];
        for (int i = 0; i < 3; ++i) {
            if (S[i] > 1e-12 * S[0] && S[i] > 0.0) {
                for (int r = 0; r < 3; ++r) U[r][i] = W[r][i] / S[i];
            } else {
                double ux = U[1][0] * U[2][1] - U[2][0] * U[1][1];
                double uy = U[2][0] * U[0][1] - U[0][0] * U[2][1];
                double uz = U[0][0] * U[1][1] - U[1][0] * U[0][1];
                double nr = sqrt(ux * ux + uy * uy + uz * uz);
                if (nr < 1e-30) { ux = 1.0; uy = 0.0; uz = 0.0; nr = 1.0; }
                U[0][i] = ux / nr; U[1][i] = uy / nr; U[2][i] = uz / nr;
            }
        }
        double r_[3][3];
        for (int i = 0; i < 3; ++i)
            for (int j = 0; j < 3; ++j)
                r_[i][j] = V[i][0] * U[j][0] + V[i][1] * U[j][1] + V[i][2] * U[j][2];
        double det = det3(r_);
        double R[3][3];
        for (int i = 0; i < 3; ++i)
            for (int j = 0; j < 3; ++j)
                R[i][j] = V[i][0] * U[j][0] + V[i][1] * U[j][1] + det * V[i][2] * U[j][2];
        double t_[3];
        for (int i = 0; i < 3; ++i)
            t_[i] = -(R[i][0] * smean[0] + R[i][1] * smean[1] + R[i][2] * smean[2]) + cmean[i];

        for (int i = 0; i < 3; ++i)
            for (int j = 0; j < 3; ++j)
                out[b * 9 + i * 3 + j] = (float)R[i][j];
        for (int i = 0; i < 3; ++i) out[NB * 9 + b * 3 + i] = (float)t_[i];
    }
}

// ---------------- launcher ----------------
extern "C" void kernel_launch(void* const* d_in, const int* in_sizes, int n_in,
                              void* d_out, int out_size, void* d_ws, size_t ws_size,
                              hipStream_t stream)
{
    const float* srcE = (const float*)d_in[0];
    const float* tgtE = (const float*)d_in[1];
    const float* src  = (const float*)d_in[2];
    const float* tgt  = (const float*)d_in[3];
    const float* temp = (const float*)d_in[4];
    const float* gum  = (const float*)d_in[5];
    float* out = (float*)d_out;
    unsigned long long* best = (unsigned long long*)d_ws;

    hipMemsetAsync(best, 0, (size_t)NB * NN * sizeof(unsigned long long), stream);

    dim3 grid(NN / TM, NN / TN, NB);
    scores_argmax<<<grid, 256, 0, stream>>>(srcE, tgtE, gum, temp, best);
    assemble<<<NB, 256, 0, stream>>>(src, tgt, best, out);
}

// Round 3
// 210.652 us; speedup vs baseline: 2.5477x; 2.5477x over previous
//
#include <hip/hip_runtime.h>
#include <hip/hip_fp16.h>
#include <math.h>

#define NB 8
#define NC 512
#define NN 2048

typedef __attribute__((ext_vector_type(8))) _Float16 f16x8;
typedef __attribute__((ext_vector_type(4))) float f32x4;

union U8 { uint32_t u[4]; f16x8 v; };

__device__ __forceinline__ unsigned f2mono(float v) {
    unsigned b = __float_as_uint(v);
    return (b & 0x80000000u) ? ~b : (b | 0x80000000u);
}

// fp32 -> (hi fp16 in low16, lo fp16 in high16); hi+lo carries ~22 mantissa bits
__device__ __forceinline__ uint32_t packsplit(float a) {
    __half h = __float2half(a);            // rne
    float hf = __half2float(h);
    __half lo = __float2half(a - hf);      // exact residual, then rne
    return (uint32_t)__half_as_ushort(h) | ((uint32_t)__half_as_ushort(lo) << 16);
}

// ---------------- Kernel 1: fp16x3 MFMA GEMM + fused gumbel argmax ----------------
// 128x128 tile, 4 waves each 64x64 (4x4 frags of 16x16x32), KB=32.
// LDS: u32-packed (hi|lo) tiles [128][32] with XOR swizzle k ^= ((n>>2)&7)<<2.
extern "C" __global__ __launch_bounds__(256, 2)
void scores_argmax(const float* __restrict__ srcE,
                   const float* __restrict__ tgtE,
                   const float* __restrict__ gum,
                   const float* __restrict__ temp,
                   unsigned long long* __restrict__ best)
{
    __shared__ uint32_t As[128 * 32];
    __shared__ uint32_t Bs[128 * 32];

    // XCD-aware bijective swizzle of the flat 2048-block grid
    const int id = blockIdx.x;
    const int flat = (id & 7) * 256 + (id >> 3);
    const int mt = flat & 15;
    const int nt = (flat >> 4) & 15;
    const int b  = flat >> 8;
    const int n0 = nt * 128, m0 = mt * 128;

    const int tid = threadIdx.x;
    const int wv = tid >> 6;            // wave 0..3
    const int l  = tid & 63;
    const int wn = wv >> 1, wm = wv & 1; // wave tile origin (wn*64, wm*64)
    const int row16 = l & 15, h = l >> 4;

    // staging map: thread covers n = 4*(tid&31)+jj, k = (tid>>5) + 8r
    const int snb = 4 * (tid & 31);
    const int skb = tid >> 5;
    const uint32_t sswz = (uint32_t)(tid & 7) << 2;   // ((snb+jj)>>2 & 7)<<2, uniform in jj

    const float* Ag = srcE + (size_t)b * NC * NN + n0 + snb;
    const float* Bg = tgtE + (size_t)b * NC * NN + m0 + snb;

    float4 pA[4], pB[4];
#pragma unroll
    for (int r = 0; r < 4; ++r) {
        pA[r] = *(const float4*)(Ag + (size_t)(skb + 8 * r) * NN);
        pB[r] = *(const float4*)(Bg + (size_t)(skb + 8 * r) * NN);
    }

    f32x4 acc[4][4];
#pragma unroll
    for (int i = 0; i < 4; ++i)
#pragma unroll
        for (int j = 0; j < 4; ++j)
            acc[i][j] = (f32x4){0.f, 0.f, 0.f, 0.f};

    for (int k0 = 0; k0 < NC; k0 += 32) {
        __syncthreads();   // previous-tile readers done
#pragma unroll
        for (int r = 0; r < 4; ++r) {
            const int k = skb + 8 * r;
            const uint32_t kx = (uint32_t)k ^ sswz;
            uint32_t* ap = &As[snb * 32 + kx];
            uint32_t* bq = &Bs[snb * 32 + kx];
            ap[0]  = packsplit(pA[r].x); ap[32] = packsplit(pA[r].y);
            ap[64] = packsplit(pA[r].z); ap[96] = packsplit(pA[r].w);
            bq[0]  = packsplit(pB[r].x); bq[32] = packsplit(pB[r].y);
            bq[64] = packsplit(pB[r].z); bq[96] = packsplit(pB[r].w);
        }
        if (k0 + 32 < NC) {
#pragma unroll
            for (int r = 0; r < 4; ++r) {
                pA[r] = *(const float4*)(Ag + (size_t)(k0 + 32 + skb + 8 * r) * NN);
                pB[r] = *(const float4*)(Bg + (size_t)(k0 + 32 + skb + 8 * r) * NN);
            }
        }
        __syncthreads();   // tile ready

        // B fragments (hi & lo) for all 4 m-subtiles
        U8 bfh[4], bfl[4];
#pragma unroll
        for (int ms = 0; ms < 4; ++ms) {
            const int m_loc = wm * 64 + ms * 16 + row16;
            const uint32_t swz = (uint32_t)((ms * 4 + (row16 >> 2)) & 7) << 2;
            const int base = m_loc * 32;
            const uint4 r0 = *(const uint4*)&Bs[base + (((uint32_t)(h * 8 + 0)) ^ swz)];
            const uint4 r1 = *(const uint4*)&Bs[base + (((uint32_t)(h * 8 + 4)) ^ swz)];
            bfh[ms].u[0] = __builtin_amdgcn_perm(r0.y, r0.x, 0x05040100u);
            bfh[ms].u[1] = __builtin_amdgcn_perm(r0.w, r0.z, 0x05040100u);
            bfh[ms].u[2] = __builtin_amdgcn_perm(r1.y, r1.x, 0x05040100u);
            bfh[ms].u[3] = __builtin_amdgcn_perm(r1.w, r1.z, 0x05040100u);
            bfl[ms].u[0] = __builtin_amdgcn_perm(r0.y, r0.x, 0x07060302u);
            bfl[ms].u[1] = __builtin_amdgcn_perm(r0.w, r0.z, 0x07060302u);
            bfl[ms].u[2] = __builtin_amdgcn_perm(r1.y, r1.x, 0x07060302u);
            bfl[ms].u[3] = __builtin_amdgcn_perm(r1.w, r1.z, 0x07060302u);
        }

#pragma unroll
        for (int ns = 0; ns < 4; ++ns) {
            const int n_loc = wn * 64 + ns * 16 + row16;
            const uint32_t swz = (uint32_t)((ns * 4 + (row16 >> 2)) & 7) << 2;
            const int base = n_loc * 32;
            const uint4 r0 = *(const uint4*)&As[base + (((uint32_t)(h * 8 + 0)) ^ swz)];
            const uint4 r1 = *(const uint4*)&As[base + (((uint32_t)(h * 8 + 4)) ^ swz)];
            U8 ah, al;
            ah.u[0] = __builtin_amdgcn_perm(r0.y, r0.x, 0x05040100u);
            ah.u[1] = __builtin_amdgcn_perm(r0.w, r0.z, 0x05040100u);
            ah.u[2] = __builtin_amdgcn_perm(r1.y, r1.x, 0x05040100u);
            ah.u[3] = __builtin_amdgcn_perm(r1.w, r1.z, 0x05040100u);
            al.u[0] = __builtin_amdgcn_perm(r0.y, r0.x, 0x07060302u);
            al.u[1] = __builtin_amdgcn_perm(r0.w, r0.z, 0x07060302u);
            al.u[2] = __builtin_amdgcn_perm(r1.y, r1.x, 0x07060302u);
            al.u[3] = __builtin_amdgcn_perm(r1.w, r1.z, 0x07060302u);
#pragma unroll
            for (int ms = 0; ms < 4; ++ms) {
                acc[ns][ms] = __builtin_amdgcn_mfma_f32_16x16x32_f16(ah.v, bfh[ms].v, acc[ns][ms], 0, 0, 0);
                acc[ns][ms] = __builtin_amdgcn_mfma_f32_16x16x32_f16(al.v, bfh[ms].v, acc[ns][ms], 0, 0, 0);
                acc[ns][ms] = __builtin_amdgcn_mfma_f32_16x16x32_f16(ah.v, bfl[ms].v, acc[ns][ms], 0, 0, 0);
            }
        }
    }

    // ---- fused gumbel + per-row argmax (C/D: col=lane&15, row=(lane>>4)*4+reg) ----
    const float SCL = 0.044194173824159216f;  // 1/sqrt(512)
    const float tau = temp[b];
#pragma unroll
    for (int ns = 0; ns < 4; ++ns) {
#pragma unroll
        for (int reg = 0; reg < 4; ++reg) {
            const int n = n0 + wn * 64 + ns * 16 + h * 4 + reg;
            const float* gr = gum + ((size_t)(b * NN + n)) * NN + m0 + wm * 64 + row16;
            unsigned long long bp = 0ULL;
#pragma unroll
            for (int ms = 0; ms < 4; ++ms) {
                float u = gr[ms * 16];
                u = fminf(fmaxf(u, 1e-6f), 1.0f - 1e-6f);
                const float g = -logf(-logf(u));
                const float val = (acc[ns][ms][reg] * SCL + g) / tau;
                const int m = m0 + wm * 64 + ms * 16 + row16;
                const unsigned long long p =
                    ((unsigned long long)f2mono(val) << 32) | (unsigned)(NN - 1 - m);
                if (p > bp) bp = p;
            }
#pragma unroll
            for (int off = 8; off > 0; off >>= 1) {
                const unsigned long long o = __shfl_xor(bp, off, 16);
                if (o > bp) bp = o;
            }
            if (row16 == 0) atomicMax(&best[(size_t)b * NN + n], bp);
        }
    }
}

// ---------------- Kernel 2: gather + covariance + 3x3 SVD + R,t ----------------
__device__ __forceinline__ double det3(const double M[3][3]) {
    return M[0][0] * (M[1][1] * M[2][2] - M[1][2] * M[2][1])
         - M[0][1] * (M[1][0] * M[2][2] - M[1][2] * M[2][0])
         + M[0][2] * (M[1][0] * M[2][1] - M[1][1] * M[2][0]);
}

extern "C" __global__ __launch_bounds__(256)
void assemble(const float* __restrict__ src, const float* __restrict__ tgt,
              const unsigned long long* __restrict__ best, float* __restrict__ out)
{
    const int b = blockIdx.x;
    const int tid = threadIdx.x;
    float P[9] = {}, Ss[3] = {}, Sc[3] = {};
    for (int n = tid; n < NN; n += 256) {
        const int m = (NN - 1) - (int)(unsigned)(best[(size_t)b * NN + n] & 0xffffffffu);
        float sv[3], cv[3];
#pragma unroll
        for (int c = 0; c < 3; ++c) {
            sv[c] = src[((size_t)b * 3 + c) * NN + n];
            cv[c] = tgt[((size_t)b * 3 + c) * NN + m];
            Ss[c] += sv[c];
            Sc[c] += cv[c];
        }
#pragma unroll
        for (int c = 0; c < 3; ++c)
#pragma unroll
            for (int d = 0; d < 3; ++d)
                P[c * 3 + d] = fmaf(sv[c], cv[d], P[c * 3 + d]);
    }

    float vals[15];
#pragma unroll
    for (int i = 0; i < 9; ++i) vals[i] = P[i];
#pragma unroll
    for (int i = 0; i < 3; ++i) { vals[9 + i] = Ss[i]; vals[12 + i] = Sc[i]; }

    __shared__ float red[4][15];
    const int lane = tid & 63, wv = tid >> 6;
#pragma unroll
    for (int i = 0; i < 15; ++i) {
        float v = vals[i];
        for (int off = 32; off > 0; off >>= 1) v += __shfl_down(v, off, 64);
        if (lane == 0) red[wv][i] = v;
    }
    __syncthreads();

    if (tid == 0) {
        double tot[15];
        for (int i = 0; i < 15; ++i)
            tot[i] = (double)red[0][i] + red[1][i] + red[2][i] + red[3][i];
        double smean[3], cmean[3], H[3][3];
        for (int c = 0; c < 3; ++c) { smean[c] = tot[9 + c] / NN; cmean[c] = tot[12 + c] / NN; }
        for (int c = 0; c < 3; ++c)
            for (int d = 0; d < 3; ++d)
                H[c][d] = tot[c * 3 + d] - tot[9 + c] * tot[12 + d] / NN;

        double W[3][3], V[3][3];
        for (int i = 0; i < 3; ++i)
            for (int j = 0; j < 3; ++j) { W[i][j] = H[i][j]; V[i][j] = (i == j) ? 1.0 : 0.0; }
        for (int sweep = 0; sweep < 60; ++sweep) {
            double offsum = 0.0;
            for (int p = 0; p < 2; ++p)
                for (int q = p + 1; q < 3; ++q) {
                    double al = 0, be = 0, ga = 0;
                    for (int r = 0; r < 3; ++r) {
                        al += W[r][p] * W[r][p];
                        be += W[r][q] * W[r][q];
                        ga += W[r][p] * W[r][q];
                    }
                    offsum += fabs(ga);
                    if (fabs(ga) <= 1e-15 * sqrt(al * be)) continue;
                    double zeta = (be - al) / (2.0 * ga);
                    double t = copysign(1.0, zeta) / (fabs(zeta) + sqrt(1.0 + zeta * zeta));
                    double c = 1.0 / sqrt(1.0 + t * t), s = c * t;
                    for (int r = 0; r < 3; ++r) {
                        double wp = W[r][p], wq = W[r][q];
                        W[r][p] = c * wp - s * wq;
                        W[r][q] = s * wp + c * wq;
                        double vp = V[r][p], vq = V[r][q];
                        V[r][p] = c * vp - s * vq;
                        V[r][q] = s * vp + c * vq;
                    }
                }
            if (offsum < 1e-13) break;
        }
        double S[3];
        for (int i = 0; i < 3; ++i)
            S[i] = sqrt(W[0][i] * W[0][i] + W[1][i] * W[1][i] + W[2][i] * W[2][i]);
        for (int i = 0; i < 2; ++i) {
            int mx = i;
            for (int j = i + 1; j < 3; ++j) if (S[j] > S[mx]) mx = j;
            if (mx != i) {
                double tS = S[i]; S[i] = S[mx]; S[mx] = tS;
                for (int r = 0; r < 3; ++r) {
                    double tw = W[r][i]; W[r][i] = W[r][mx]; W[r][mx] = tw;
                    double tv = V[r][i]; V[r][i] = V[r][mx]; V[r][mx] = tv;
                }
            }
        }
        double U[3][3];
        for (int i = 0; i < 3; ++i) {
            if (S[i] > 1e-12 * S[0] && S[i] > 0.0) {
                for (int r = 0; r < 3; ++r) U[r][i] = W[r][i] / S[i];
            } else {
                double ux = U[1][0] * U[2][1] - U[2][0] * U[1][1];
                double uy = U[2][0] * U[0][1] - U[0][0] * U[2][1];
                double uz = U[0][0] * U[1][1] - U[1][0] * U[0][1];
                double nr = sqrt(ux * ux + uy * uy + uz * uz);
                if (nr < 1e-30) { ux = 1.0; uy = 0.0; uz = 0.0; nr = 1.0; }
                U[0][i] = ux / nr; U[1][i] = uy / nr; U[2][i] = uz / nr;
            }
        }
        double r_[3][3];
        for (int i = 0; i < 3; ++i)
            for (int j = 0; j < 3; ++j)
                r_[i][j] = V[i][0] * U[j][0] + V[i][1] * U[j][1] + V[i][2] * U[j][2];
        double det = det3(r_);
        double R[3][3];
        for (int i = 0; i < 3; ++i)
            for (int j = 0; j < 3; ++j)
                R[i][j] = V[i][0] * U[j][0] + V[i][1] * U[j][1] + det * V[i][2] * U[j][2];
        double t_[3];
        for (int i = 0; i < 3; ++i)
            t_[i] = -(R[i][0] * smean[0] + R[i][1] * smean[1] + R[i][2] * smean[2]) + cmean[i];

        for (int i = 0; i < 3; ++i)
            for (int j = 0; j < 3; ++j)
                out[b * 9 + i * 3 + j] = (float)R[i][j];
        for (int i = 0; i < 3; ++i) out[NB * 9 + b * 3 + i] = (float)t_[i];
    }
}

// ---------------- launcher ----------------
extern "C" void kernel_launch(void* const* d_in, const int* in_sizes, int n_in,
                              void* d_out, int out_size, void* d_ws, size_t ws_size,
                              hipStream_t stream)
{
    const float* srcE = (const float*)d_in[0];
    const float* tgtE = (const float*)d_in[1];
    const float* src  = (const float*)d_in[2];
    const float* tgt  = (const float*)d_in[3];
    const float* temp = (const float*)d_in[4];
    const float* gum  = (const float*)d_in[5];
    float* out = (float*)d_out;
    unsigned long long* best = (unsigned long long*)d_ws;

    hipMemsetAsync(best, 0, (size_t)NB * NN * sizeof(unsigned long long), stream);

    scores_argmax<<<2048, 256, 0, stream>>>(srcE, tgtE, gum, temp, best);
    assemble<<<NB, 256, 0, stream>>>(src, tgt, best, out);
}